// Round 10
// baseline (804.049 us; speedup 1.0000x reference)
//
#include <hip/hip_runtime.h>
#include <hip/hip_cooperative_groups.h>
#include <math.h>

namespace cg = cooperative_groups;

#define IN_DIM 128
#define HID 64
#define OUT_DIM 128
#define ELL_W 64
constexpr float EPS = 1e-5f;

typedef short short8 __attribute__((ext_vector_type(8)));
typedef float f32x4  __attribute__((ext_vector_type(4)));

// ---------------------------------------------------------------------------
// ONE cooperative kernel, 5 phases (grid.sync between):
//   P0: zero ws-stats + deg; blocks 0..15 also do wprep (Bfrag)
//   P1: column stats (sum / sumsq) -> ws[0..256)
//   P2: ELL fill — EXACT r0 loop (plain scalar loads; the only config measured
//       at 12.2 G-edges/s; NT/vector variants all ran at 6-11 G/s)
//   P3: layernorm+QKV MFMA, grid-stride over 64-row tiles -> qv rows
//       (stride 192: q@0 | v@64), kb rows
//   P4: gather — wave per node, 4-edge groups x 16 dims (proven r2/r8 core)
// Rationale: kernel-time sum ~320us vs 409us wall across 6 dispatches ->
// ~90us of inter-dispatch gap/drain is the largest attackable cost.
// ws layout: float[0,256) stats | int deg[N] | int ell[N*64] |
//            bf16 qv[(N+64)*192] | bf16 kb[(N+64)*64] | bf16 Bfrag[64*64*8]
// ---------------------------------------------------------------------------

__device__ inline ushort f2bf(float x) {          // RNE float->bf16 bits
    __bf16 h = (__bf16)x;
    return *reinterpret_cast<ushort*>(&h);
}
__device__ inline short f2bfs(float x) {
    __bf16 h = (__bf16)x;
    return *reinterpret_cast<short*>(&h);
}
__device__ inline float bf2f(ushort u) {
    union { unsigned u; float f; } c; c.u = ((unsigned)u) << 16;
    return c.f;
}
__device__ inline float4 bf4_to_f4(ushort4 u) {
    return make_float4(bf2f(u.x), bf2f(u.y), bf2f(u.z), bf2f(u.w));
}

__global__ __launch_bounds__(256, 4) void mega(
    const float* __restrict__ feat,
    const int* __restrict__ src, const int* __restrict__ dst,
    const float* __restrict__ gamma, const float* __restrict__ beta,
    const float* __restrict__ Wq, const float* __restrict__ bq,
    const float* __restrict__ Wk, const float* __restrict__ Wv,
    const float* __restrict__ We,
    float* __restrict__ ws, int* __restrict__ deg, int* __restrict__ ell,
    ushort* __restrict__ qvb, ushort* __restrict__ kb,
    ushort* __restrict__ Bfrag, float* __restrict__ out,
    int n_nodes, int n_edges, int mb)
{
    cg::grid_group gg = cg::this_grid();
    __shared__ float smem[512];
    int t    = threadIdx.x;
    int G    = (int)gridDim.x;
    int gtid = (int)blockIdx.x * 256 + t;
    int gsz  = G * 256;
    int w    = t >> 6;
    int lane = t & 63;

    // ---------------- P0: zero + wprep ----------------
    for (int i = gtid; i < 256; i += gsz) ws[i] = 0.f;
    for (int i = gtid; i < n_nodes; i += gsz) deg[i] = 0;
    if (blockIdx.x < 16) {
        int gid  = (int)blockIdx.x * 256 + t;    // 0..4095
        int f    = gid >> 6;
        int l    = gid & 63;
        int kc = f & 3, ct = (f >> 2) & 3, ww = f >> 4;
        int col   = ww * 64 + ct * 16 + (l & 15);
        int kbase = kc * 32 + (l >> 4) * 8;
        ushort tmp[8];
        #pragma unroll
        for (int j = 0; j < 8; j++) {
            int k = kbase + j;
            float val;
            if (col < 64)       val = Wq[k * HID + col];
            else if (col < 128) val = Wk[k * HID + (col - 64)];
            else                val = Wv[k * OUT_DIM + (col - 128)];
            tmp[j] = f2bf(val);
        }
        ushort* d = &Bfrag[(f * 64 + l) * 8];
        *(ushort4*)d       = make_ushort4(tmp[0], tmp[1], tmp[2], tmp[3]);
        *(ushort4*)(d + 4) = make_ushort4(tmp[4], tmp[5], tmp[6], tmp[7]);
    }
    gg.sync();

    // ---------------- P1: stats ----------------
    {
        int col  = t & 127;
        int half = t >> 7;
        float sum = 0.f, sq = 0.f;
        for (int r = (int)blockIdx.x * 2 + half; r < n_nodes; r += G * 2) {
            float x = feat[r * IN_DIM + col];
            sum += x; sq += x * x;
        }
        smem[t] = sum; smem[256 + t] = sq;
        __syncthreads();
        if (t < 128) {
            sum = smem[t] + smem[t + 128];
            sq  = smem[256 + t] + smem[256 + t + 128];
            unsafeAtomicAdd(&ws[t], sum);
            unsafeAtomicAdd(&ws[128 + t], sq);
        }
    }
    gg.sync();

    // ---------------- P2: ELL fill (r0-exact) ----------------
    for (int e = gtid; e < n_edges; e += gsz) {
        int d = dst[e];
        int s = src[e];
        int pos = atomicAdd(&deg[d], 1);
        if (pos < ELL_W) ell[(size_t)d * ELL_W + pos] = s;
    }
    gg.sync();

    // ---------------- P3: MFMA layernorm+QKV ----------------
    {
        if (t < 128) {
            float inv_n = 1.0f / (float)n_nodes;
            float mean = ws[t] * inv_n;
            float var  = ws[128 + t] * inv_n - mean * mean;
            float s    = gamma[t] * rsqrtf(var + EPS);
            smem[t] = s; smem[128 + t] = beta[t] - mean * s;
        }
        int m    = lane & 15;
        int quad = lane >> 4;
        int nm1  = n_nodes - 1;
        short8 bfr[16];
        #pragma unroll
        for (int f = 0; f < 16; f++)
            bfr[f] = *(const short8*)&Bfrag[((w * 16 + f) * 64 + lane) * 8];
        __syncthreads();
        const float* sc = smem;
        const float* sh = smem + 128;

        for (int mi = (int)blockIdx.x; mi < mb; mi += G) {
            int row0 = mi * 64;
            f32x4 acc[4][4] = {};
            #pragma unroll
            for (int kc = 0; kc < 4; kc++) {
                int koff = kc * 32 + quad * 8;
                float4 sc0 = *(const float4*)&sc[koff];
                float4 sc1 = *(const float4*)&sc[koff + 4];
                float4 sh0 = *(const float4*)&sh[koff];
                float4 sh1 = *(const float4*)&sh[koff + 4];
                short8 afr[4];
                #pragma unroll
                for (int rt = 0; rt < 4; rt++) {
                    int row = row0 + rt * 16 + m;
                    row = row < nm1 ? row : nm1;        // clamp OOB reads
                    const float* fp = &feat[(size_t)row * IN_DIM + koff];
                    float4 x0 = *(const float4*)fp;
                    float4 x1 = *(const float4*)(fp + 4);
                    afr[rt][0] = f2bfs(x0.x * sc0.x + sh0.x);
                    afr[rt][1] = f2bfs(x0.y * sc0.y + sh0.y);
                    afr[rt][2] = f2bfs(x0.z * sc0.z + sh0.z);
                    afr[rt][3] = f2bfs(x0.w * sc0.w + sh0.w);
                    afr[rt][4] = f2bfs(x1.x * sc1.x + sh1.x);
                    afr[rt][5] = f2bfs(x1.y * sc1.y + sh1.y);
                    afr[rt][6] = f2bfs(x1.z * sc1.z + sh1.z);
                    afr[rt][7] = f2bfs(x1.w * sc1.w + sh1.w);
                }
                #pragma unroll
                for (int rt = 0; rt < 4; rt++)
                    #pragma unroll
                    for (int ct = 0; ct < 4; ct++)
                        acc[rt][ct] = __builtin_amdgcn_mfma_f32_16x16x32_bf16(
                            afr[rt], bfr[ct * 4 + kc], acc[rt][ct], 0, 0, 0);
            }

            // w==0: q -> qv@0 ; w==1: k -> kb ; w==2/3: v -> qv@64/128
            ushort* base; int ld, cl;
            if (w == 1)      { base = kb;  ld = HID; cl = 0; }
            else             { base = qvb; ld = 192; cl = (w == 0) ? 0 : 64 * (w - 1); }

            #pragma unroll
            for (int ct = 0; ct < 4; ct++) {
                int col = cl + ct * 16 + m;
                float bias = (w == 0) ? bq[ct * 16 + m] : 0.f;
                #pragma unroll
                for (int rt = 0; rt < 4; rt++) {
                    int r0 = row0 + rt * 16 + quad * 4;
                    #pragma unroll
                    for (int r = 0; r < 4; r++)
                        base[(size_t)(r0 + r) * ld + col] = f2bf(acc[rt][ct][r] + bias);
                }
            }
        }
    }
    gg.sync();

    // ---------------- P4: gather (wave per node) ----------------
    {
        int h   = lane & 15;
        int sub = lane >> 4;
        float4 we = *(const float4*)&We[4 * h];
        const float L2E = 1.4426950408889634f;
        we.x *= L2E; we.y *= L2E; we.z *= L2E; we.w *= L2E;

        for (int node = (int)blockIdx.x * 4 + w; node < n_nodes; node += G * 4) {
            int cnt = deg[node];
            cnt = cnt < ELL_W ? cnt : ELL_W;
            int ob = node * OUT_DIM + 4 * h;

            if (cnt == 0) {
                if (sub == 0) {
                    float4 z = make_float4(0.f, 0.f, 0.f, 0.f);
                    *(float4*)&out[ob]      = z;
                    *(float4*)&out[ob + 64] = z;
                }
                continue;
            }

            const int* row = &ell[(size_t)node * ELL_W];
            float4 kd = bf4_to_f4(*(const ushort4*)&kb[node * HID + 4 * h]);

            float4 o0 = make_float4(0.f, 0.f, 0.f, 0.f);
            float4 o1 = make_float4(0.f, 0.f, 0.f, 0.f);
            float ssum = 0.f;

            for (int p0 = 0; p0 < cnt; p0 += 4) {
                int p = p0 + sub;
                bool act = (p < cnt);
                int sN = row[act ? p : 0];
                const ushort* qv = qvb + (size_t)sN * 192;
                float4 qq = bf4_to_f4(*(const ushort4*)(qv + 4 * h));
                float tt;
                tt  = we.x * __fdividef(1.f, 1.f + __expf(-(qq.x + kd.x)));
                tt += we.y * __fdividef(1.f, 1.f + __expf(-(qq.y + kd.y)));
                tt += we.z * __fdividef(1.f, 1.f + __expf(-(qq.z + kd.z)));
                tt += we.w * __fdividef(1.f, 1.f + __expf(-(qq.w + kd.w)));
                tt += __shfl_xor(tt, 1);
                tt += __shfl_xor(tt, 2);
                tt += __shfl_xor(tt, 4);
                tt += __shfl_xor(tt, 8);
                float exv = act ? exp2f(tt) : 0.f;   // we pre-scaled by log2(e)
                ssum += exv;
                float4 v0 = bf4_to_f4(*(const ushort4*)(qv + 64 + 4 * h));
                float4 v1 = bf4_to_f4(*(const ushort4*)(qv + 128 + 4 * h));
                o0.x += exv * v0.x; o0.y += exv * v0.y;
                o0.z += exv * v0.z; o0.w += exv * v0.w;
                o1.x += exv * v1.x; o1.y += exv * v1.y;
                o1.z += exv * v1.z; o1.w += exv * v1.w;
            }

            ssum += __shfl_xor(ssum, 16); ssum += __shfl_xor(ssum, 32);
            o0.x += __shfl_xor(o0.x, 16); o0.x += __shfl_xor(o0.x, 32);
            o0.y += __shfl_xor(o0.y, 16); o0.y += __shfl_xor(o0.y, 32);
            o0.z += __shfl_xor(o0.z, 16); o0.z += __shfl_xor(o0.z, 32);
            o0.w += __shfl_xor(o0.w, 16); o0.w += __shfl_xor(o0.w, 32);
            o1.x += __shfl_xor(o1.x, 16); o1.x += __shfl_xor(o1.x, 32);
            o1.y += __shfl_xor(o1.y, 16); o1.y += __shfl_xor(o1.y, 32);
            o1.z += __shfl_xor(o1.z, 16); o1.z += __shfl_xor(o1.z, 32);
            o1.w += __shfl_xor(o1.w, 16); o1.w += __shfl_xor(o1.w, 32);

            if (sub == 0) {
                float inv = (ssum > 0.f) ? __fdividef(1.f, ssum) : 0.f;
                o0.x *= inv; o0.y *= inv; o0.z *= inv; o0.w *= inv;
                o1.x *= inv; o1.y *= inv; o1.z *= inv; o1.w *= inv;
                *(float4*)&out[ob]      = o0;
                *(float4*)&out[ob + 64] = o1;
            }
        }
    }
}

extern "C" void kernel_launch(void* const* d_in, const int* in_sizes, int n_in,
                              void* d_out, int out_size, void* d_ws, size_t ws_size,
                              hipStream_t stream)
{
    const float* feat  = (const float*)d_in[0];
    const int*   src   = (const int*)d_in[1];
    const int*   dst   = (const int*)d_in[2];
    const float* gamma = (const float*)d_in[3];
    const float* beta  = (const float*)d_in[4];
    const float* Wq    = (const float*)d_in[5];
    const float* bq    = (const float*)d_in[6];
    const float* Wk    = (const float*)d_in[7];
    const float* Wv    = (const float*)d_in[8];
    const float* We    = (const float*)d_in[9];

    int n_nodes = in_sizes[0] / IN_DIM;
    int n_edges = in_sizes[1];
    int n_pad   = n_nodes + 64;             // store slack for branchless epilogue
    int mb      = (n_nodes + 63) / 64;

    float* ws = (float*)d_ws;

    // ---- workspace carve-up ----
    int* deg = (int*)(ws + 256);
    int* ell = deg + n_nodes;
    size_t off = 256 + (size_t)n_nodes * (1 + ELL_W);
    off = (off + 3) & ~(size_t)3;
    ushort* qvb   = (ushort*)(ws + off);
    ushort* kb    = qvb + (size_t)n_pad * 192;
    ushort* Bfrag = kb + (size_t)n_pad * HID;
    float*  outp  = (float*)d_out;

    // ---- cooperative grid size: blocksPerCU (from occupancy API) x numCU ----
    static int s_grid = 0;
    if (s_grid == 0) {
        int maxB = 0;
        (void)hipOccupancyMaxActiveBlocksPerMultiprocessor(
            &maxB, reinterpret_cast<const void*>(mega), 256, 0);
        if (maxB < 1) maxB = 1;
        if (maxB > 8) maxB = 8;
        hipDeviceProp_t prop;
        int dev = 0;
        (void)hipGetDevice(&dev);
        int ncu = 256;
        if (hipGetDeviceProperties(&prop, dev) == hipSuccess &&
            prop.multiProcessorCount > 0)
            ncu = prop.multiProcessorCount;
        s_grid = ncu * maxB;
    }

    void* args[] = {
        (void*)&feat, (void*)&src, (void*)&dst, (void*)&gamma, (void*)&beta,
        (void*)&Wq, (void*)&bq, (void*)&Wk, (void*)&Wv, (void*)&We,
        (void*)&ws, (void*)&deg, (void*)&ell, (void*)&qvb, (void*)&kb,
        (void*)&Bfrag, (void*)&outp, (void*)&n_nodes, (void*)&n_edges,
        (void*)&mb
    };
    (void)hipLaunchCooperativeKernel(reinterpret_cast<void*>(mega),
                                     dim3(s_grid), dim3(256), args, 0, stream);
}

// Round 11
// 412.663 us; speedup vs baseline: 1.9484x; 1.9484x over previous
//
#include <hip/hip_runtime.h>
#include <math.h>

#define IN_DIM 128
#define HID 64
#define OUT_DIM 128
#define ELL_W 64
#define NPART 8
constexpr float EPS = 1e-5f;

typedef short short8 __attribute__((ext_vector_type(8)));
typedef float f32x4  __attribute__((ext_vector_type(4)));
typedef int   i32x4  __attribute__((ext_vector_type(4)));

// ---------------------------------------------------------------------------
// 5 dispatches, each component at its measured-best configuration:
//   memset(stats+deg) -> pre(stats || wprep) -> fill_ell_part (r2-verbatim,
//   fastest measured fill: <114.7us) -> mfma_qkv -> gather.
// Cross-round ledger: per-dispatch overhead ~14us; fused fill halves its rate
// (r8/r9: 6.1-6.3 G-edges/s fused vs 12-14 standalone) -> never fuse fill.
// ws: float[0,256) stats | int deg[N] | int ell[N*64] |
//     bf16 qv[(N+64)*192] (q 64 | v 128 per row) | bf16 kb[(N+64)*64] |
//     bf16 Bfrag[64*64*8]
// Numerics: q,k stored pre-scaled by log2(e) so gather's sigmoid uses exp2f
// (v_exp only, no mul); We pre-scaled by log2(e) in gather for the outer exp2.
// ---------------------------------------------------------------------------

__device__ inline ushort f2bf(float x) {          // RNE float->bf16 bits
    __bf16 h = (__bf16)x;
    return *reinterpret_cast<ushort*>(&h);
}
__device__ inline short f2bfs(float x) {
    __bf16 h = (__bf16)x;
    return *reinterpret_cast<short*>(&h);
}
__device__ inline float bf2f(ushort u) {
    union { unsigned u; float f; } c; c.u = ((unsigned)u) << 16;
    return c.f;
}
__device__ inline float4 bf4_to_f4(ushort4 u) {
    return make_float4(bf2f(u.x), bf2f(u.y), bf2f(u.z), bf2f(u.w));
}

// ---------------- pre: stats (blocks 0..255) | wprep (blocks 256..271) -----
__global__ __launch_bounds__(256) void pre(
    const float* __restrict__ feat, float* __restrict__ ws, int n_nodes,
    const float* __restrict__ Wq, const float* __restrict__ Wk,
    const float* __restrict__ Wv, ushort* __restrict__ Bfrag)
{
    int t = threadIdx.x;
    if (blockIdx.x < 256) {
        __shared__ float redS[256], redQ[256];
        int col  = t & 127;
        int half = t >> 7;
        float sum = 0.f, sq = 0.f;
        for (int r = blockIdx.x * 2 + half; r < n_nodes; r += 512) {
            float x = feat[r * IN_DIM + col];
            sum += x; sq += x * x;
        }
        redS[t] = sum; redQ[t] = sq;
        __syncthreads();
        if (t < 128) {
            sum = redS[t] + redS[t + 128];
            sq  = redQ[t] + redQ[t + 128];
            unsafeAtomicAdd(&ws[col], sum);
            unsafeAtomicAdd(&ws[128 + col], sq);
        }
    } else {
        int gid  = (blockIdx.x - 256) * 256 + t;     // 0..4095
        int f    = gid >> 6;
        int lane = gid & 63;
        int kc = f & 3, ct = (f >> 2) & 3, w = f >> 4;
        int col   = w * 64 + ct * 16 + (lane & 15);
        int kbase = kc * 32 + (lane >> 4) * 8;
        ushort tmp[8];
        #pragma unroll
        for (int j = 0; j < 8; j++) {
            int k = kbase + j;
            float val;
            if (col < 64)       val = Wq[k * HID + col];
            else if (col < 128) val = Wk[k * HID + (col - 64)];
            else                val = Wv[k * OUT_DIM + (col - 128)];
            tmp[j] = f2bf(val);
        }
        ushort* d = &Bfrag[(f * 64 + lane) * 8];
        *(ushort4*)d       = make_ushort4(tmp[0], tmp[1], tmp[2], tmp[3]);
        *(ushort4*)(d + 4) = make_ushort4(tmp[4], tmp[5], tmp[6], tmp[7]);
    }
}

// ---------------- ELL build: dst-partitioned (r2-verbatim, <114.7us) -------
__global__ __launch_bounds__(256) void fill_ell_part(
    const int* __restrict__ src, const int* __restrict__ dst,
    int* __restrict__ deg, int* __restrict__ ell,
    int n_edges, int part_size)
{
    int p  = blockIdx.x & (NPART - 1);
    int gb = blockIdx.x >> 3;          // block rank within partition group
    int nb = gridDim.x >> 3;           // blocks per partition group
    unsigned lo = (unsigned)(p * part_size);
    unsigned ps = (unsigned)part_size;

    int idx    = gb * 256 + threadIdx.x;
    int stride = nb * 256;
    int n4     = n_edges >> 2;

    const i32x4* dst4 = reinterpret_cast<const i32x4*>(dst);
    const i32x4* src4 = reinterpret_cast<const i32x4*>(src);

    for (int i = idx; i < n4; i += stride) {
        i32x4 d4 = __builtin_nontemporal_load(dst4 + i);
        i32x4 s4 = __builtin_nontemporal_load(src4 + i);
        #pragma unroll
        for (int j = 0; j < 4; j++) {
            unsigned d = (unsigned)d4[j];
            if (d - lo < ps) {
                int pos = atomicAdd(&deg[d], 1);
                if (pos < ELL_W) ell[(size_t)d * ELL_W + pos] = s4[j];
            }
        }
    }
    for (int e = (n4 << 2) + idx; e < n_edges; e += stride) {
        unsigned d = (unsigned)dst[e];
        if (d - lo < ps) {
            int pos = atomicAdd(&deg[d], 1);
            if (pos < ELL_W) ell[(size_t)d * ELL_W + pos] = src[e];
        }
    }
}

// ---------------- MFMA layernorm+QKV -> qv rows (192), kb rows -------------
// q,k outputs scaled by log2(e) so gather's sigmoid is a bare v_exp (exp2f).
__global__ __launch_bounds__(256) void mfma_qkv(
    const float* __restrict__ feat, const ushort* __restrict__ Bfrag,
    const float* __restrict__ bq,
    const float* __restrict__ gamma, const float* __restrict__ beta,
    const float* __restrict__ stats,
    ushort* __restrict__ qvb, ushort* __restrict__ kb,
    int n_nodes)
{
    __shared__ float sc[IN_DIM], sh[IN_DIM];
    int tid = threadIdx.x;
    if (tid < 128) {
        float inv_n = 1.0f / (float)n_nodes;
        float mean = stats[tid] * inv_n;
        float var  = stats[128 + tid] * inv_n - mean * mean;
        float s    = gamma[tid] * rsqrtf(var + EPS);
        sc[tid] = s; sh[tid] = beta[tid] - mean * s;
    }

    int w    = tid >> 6;
    int lane = tid & 63;
    int row0 = blockIdx.x * 64;
    int m    = lane & 15;
    int quad = lane >> 4;
    int nm1  = n_nodes - 1;

    short8 bfr[16];
    #pragma unroll
    for (int f = 0; f < 16; f++)
        bfr[f] = *(const short8*)&Bfrag[((w * 16 + f) * 64 + lane) * 8];

    __syncthreads();

    f32x4 acc[4][4] = {};   // [row-tile][col-tile]

    #pragma unroll
    for (int kc = 0; kc < 4; kc++) {
        int koff = kc * 32 + quad * 8;
        float4 sc0 = *(const float4*)&sc[koff];
        float4 sc1 = *(const float4*)&sc[koff + 4];
        float4 sh0 = *(const float4*)&sh[koff];
        float4 sh1 = *(const float4*)&sh[koff + 4];
        short8 afr[4];
        #pragma unroll
        for (int rt = 0; rt < 4; rt++) {
            int row = row0 + rt * 16 + m;
            row = row < nm1 ? row : nm1;            // clamp OOB reads
            const float* fp = &feat[(size_t)row * IN_DIM + koff];
            float4 x0 = *(const float4*)fp;
            float4 x1 = *(const float4*)(fp + 4);
            afr[rt][0] = f2bfs(x0.x * sc0.x + sh0.x);
            afr[rt][1] = f2bfs(x0.y * sc0.y + sh0.y);
            afr[rt][2] = f2bfs(x0.z * sc0.z + sh0.z);
            afr[rt][3] = f2bfs(x0.w * sc0.w + sh0.w);
            afr[rt][4] = f2bfs(x1.x * sc1.x + sh1.x);
            afr[rt][5] = f2bfs(x1.y * sc1.y + sh1.y);
            afr[rt][6] = f2bfs(x1.z * sc1.z + sh1.z);
            afr[rt][7] = f2bfs(x1.w * sc1.w + sh1.w);
        }
        #pragma unroll
        for (int rt = 0; rt < 4; rt++)
            #pragma unroll
            for (int ct = 0; ct < 4; ct++)
                acc[rt][ct] = __builtin_amdgcn_mfma_f32_16x16x32_bf16(
                    afr[rt], bfr[ct * 4 + kc], acc[rt][ct], 0, 0, 0);
    }

    // w==0: q*L2E -> qv@0 ; w==1: k*L2E -> kb ; w==2/3: v -> qv@64/128
    const float L2E = 1.4426950408889634f;
    ushort* base; int ld, cl;
    float scale = (w <= 1) ? L2E : 1.f;
    if (w == 1)      { base = kb;  ld = HID; cl = 0; }
    else             { base = qvb; ld = 192; cl = (w == 0) ? 0 : 64 * (w - 1); }

    #pragma unroll
    for (int ct = 0; ct < 4; ct++) {
        int col = cl + ct * 16 + m;
        float bias = (w == 0) ? bq[ct * 16 + m] : 0.f;
        #pragma unroll
        for (int rt = 0; rt < 4; rt++) {
            int r0 = row0 + rt * 16 + quad * 4;
            #pragma unroll
            for (int r = 0; r < 4; r++)
                base[(size_t)(r0 + r) * ld + col] =
                    f2bf((acc[rt][ct][r] + bias) * scale);
        }
    }
}

// ---------------- gather: 4-edge groups x 16 dims, global ELL --------------
// lane = sub*16 + h. qv row: [q 64 | v 128] bf16, stride 192.
// q,k pre-scaled by log2(e) -> sigmoid = rcp(1 + exp2(-(q'+k'))).
// We pre-scaled by log2(e) -> outer exp is exp2f.
__global__ __launch_bounds__(256) void gather_ell(
    const int* __restrict__ deg, const int* __restrict__ ell,
    const ushort* __restrict__ qvb, const ushort* __restrict__ kb,
    const float* __restrict__ We,
    float* __restrict__ out, int n_nodes)
{
    int node = (blockIdx.x * 256 + threadIdx.x) >> 6;
    int lane = threadIdx.x & 63;
    if (node >= n_nodes) return;
    int h   = lane & 15;
    int sub = lane >> 4;
    int cnt = deg[node];
    cnt = cnt < ELL_W ? cnt : ELL_W;

    if (cnt == 0) {
        if (sub == 0) {
            float4 z = make_float4(0.f, 0.f, 0.f, 0.f);
            *(float4*)&out[node * OUT_DIM + 4 * h]      = z;
            *(float4*)&out[node * OUT_DIM + 64 + 4 * h] = z;
        }
        return;
    }

    const int* row = &ell[(size_t)node * ELL_W];
    float4 kd = bf4_to_f4(*(const ushort4*)&kb[node * HID + 4 * h]);
    float4 we = *(const float4*)&We[4 * h];
    const float L2E = 1.4426950408889634f;
    we.x *= L2E; we.y *= L2E; we.z *= L2E; we.w *= L2E;

    float4 o0 = make_float4(0.f, 0.f, 0.f, 0.f);
    float4 o1 = make_float4(0.f, 0.f, 0.f, 0.f);
    float ssum = 0.f;

    for (int p0 = 0; p0 < cnt; p0 += 4) {
        int p = p0 + sub;
        bool act = (p < cnt);
        int sN = row[act ? p : 0];
        const ushort* qv = qvb + (size_t)sN * 192;
        float4 qq = bf4_to_f4(*(const ushort4*)(qv + 4 * h));
        float t;
        t  = we.x * __fdividef(1.f, 1.f + exp2f(-(qq.x + kd.x)));
        t += we.y * __fdividef(1.f, 1.f + exp2f(-(qq.y + kd.y)));
        t += we.z * __fdividef(1.f, 1.f + exp2f(-(qq.z + kd.z)));
        t += we.w * __fdividef(1.f, 1.f + exp2f(-(qq.w + kd.w)));
        t += __shfl_xor(t, 1);
        t += __shfl_xor(t, 2);
        t += __shfl_xor(t, 4);
        t += __shfl_xor(t, 8);
        float exv = act ? exp2f(t) : 0.f;     // t already includes log2(e)
        ssum += exv;
        float4 v0 = bf4_to_f4(*(const ushort4*)(qv + 64 + 4 * h));
        float4 v1 = bf4_to_f4(*(const ushort4*)(qv + 128 + 4 * h));
        o0.x += exv * v0.x; o0.y += exv * v0.y;
        o0.z += exv * v0.z; o0.w += exv * v0.w;
        o1.x += exv * v1.x; o1.y += exv * v1.y;
        o1.z += exv * v1.z; o1.w += exv * v1.w;
    }

    ssum += __shfl_xor(ssum, 16); ssum += __shfl_xor(ssum, 32);
    o0.x += __shfl_xor(o0.x, 16); o0.x += __shfl_xor(o0.x, 32);
    o0.y += __shfl_xor(o0.y, 16); o0.y += __shfl_xor(o0.y, 32);
    o0.z += __shfl_xor(o0.z, 16); o0.z += __shfl_xor(o0.z, 32);
    o0.w += __shfl_xor(o0.w, 16); o0.w += __shfl_xor(o0.w, 32);
    o1.x += __shfl_xor(o1.x, 16); o1.x += __shfl_xor(o1.x, 32);
    o1.y += __shfl_xor(o1.y, 16); o1.y += __shfl_xor(o1.y, 32);
    o1.z += __shfl_xor(o1.z, 16); o1.z += __shfl_xor(o1.z, 32);
    o1.w += __shfl_xor(o1.w, 16); o1.w += __shfl_xor(o1.w, 32);

    if (sub == 0) {
        float inv = (ssum > 0.f) ? __fdividef(1.f, ssum) : 0.f;
        o0.x *= inv; o0.y *= inv; o0.z *= inv; o0.w *= inv;
        o1.x *= inv; o1.y *= inv; o1.z *= inv; o1.w *= inv;
        *(float4*)&out[node * OUT_DIM + 4 * h]      = o0;
        *(float4*)&out[node * OUT_DIM + 64 + 4 * h] = o1;
    }
}

extern "C" void kernel_launch(void* const* d_in, const int* in_sizes, int n_in,
                              void* d_out, int out_size, void* d_ws, size_t ws_size,
                              hipStream_t stream)
{
    const float* feat  = (const float*)d_in[0];
    const int*   src   = (const int*)d_in[1];
    const int*   dst   = (const int*)d_in[2];
    const float* gamma = (const float*)d_in[3];
    const float* beta  = (const float*)d_in[4];
    const float* Wq    = (const float*)d_in[5];
    const float* bq    = (const float*)d_in[6];
    const float* Wk    = (const float*)d_in[7];
    const float* Wv    = (const float*)d_in[8];
    const float* We    = (const float*)d_in[9];

    int n_nodes = in_sizes[0] / IN_DIM;
    int n_edges = in_sizes[1];
    int n_pad   = n_nodes + 64;             // store slack for branchless epilogue
    int part_size = (n_nodes + NPART - 1) / NPART;

    float* ws = (float*)d_ws;

    // ---- workspace carve-up ----
    int* deg = (int*)(ws + 256);
    int* ell = deg + n_nodes;
    size_t off = 256 + (size_t)n_nodes * (1 + ELL_W);
    off = (off + 3) & ~(size_t)3;
    ushort* qvb   = (ushort*)(ws + off);
    ushort* kb    = qvb + (size_t)n_pad * 192;
    ushort* Bfrag = kb + (size_t)n_pad * HID;

    hipMemsetAsync(ws, 0, (256 + (size_t)n_nodes) * sizeof(float), stream);
    pre<<<272, 256, 0, stream>>>(feat, ws, n_nodes, Wq, Wk, Wv, Bfrag);
    fill_ell_part<<<2048, 256, 0, stream>>>(
        src, dst, deg, ell, n_edges, part_size);
    mfma_qkv<<<(n_nodes + 63) / 64, 256, 0, stream>>>(
        feat, Bfrag, bq, gamma, beta, ws, qvb, kb, n_nodes);
    long long g_threads = (long long)n_nodes * 64;
    gather_ell<<<(int)((g_threads + 255) / 256), 256, 0, stream>>>(
        deg, ell, qvb, kb, We, (float*)d_out, n_nodes);
}